// Round 8
// baseline (471.105 us; speedup 1.0000x reference)
//
#include <hip/hip_runtime.h>
#include <cmath>

#define TT 500
#define NTOT 2048000       // T*B*C elements
#define WW 20

// ---------------------------------------------------------------------------
// QKV GEMM: A fp32 [M,512], 3 weights. BM=64,BN=128,BK=16, 8x8 microtile,
// 128 threads (2 waves). Grid (63,12)=756 blocks -> ALL co-resident, no tail.
// LDS ratio 1.0 B/FMA (best without acc overflow). Fused column stats.
// ---------------------------------------------------------------------------
__global__ __launch_bounds__(128) void gemm_f_k(
    const float* __restrict__ A,
    const float* __restrict__ W0, const float* __restrict__ W1, const float* __restrict__ W2,
    float* __restrict__ out, float* __restrict__ colpart, int M)
{
    __shared__ __align__(16) float smem[3200];   // As[16][68] | Bs[16][132]; red aliases
    float* As = smem;            // 1088
    float* Bs = smem + 1088;     // 2112
    int tid = threadIdx.x;
    int mBase = blockIdx.x * 64;
    int nBase = blockIdx.y * 128;
    int wsel = nBase >> 9;
    const float* Wp = (wsel == 0) ? W0 : ((wsel == 1) ? W1 : W2);
    int col0 = nBase & 511;
    int ty = tid >> 4, tx = tid & 15;        // ty 0..7 (m), tx 0..15 (n)
    int aRow = tid >> 1, aK = (tid & 1) * 8; // A: 64 rows x 16k, 8 floats/thread
    int bRow4 = tid >> 2, bK = (tid & 3) * 4;// B: 128 rows x 16k, 16 floats/thread
    float acc[8][8] = {};
    float4 pa[2], pb[4];

    auto loadT = [&](int kt) {
        int m = mBase + aRow;
        if (m < M) {
            const float* ap = A + (size_t)m * 512 + kt + aK;
            pa[0] = *(const float4*)ap;
            pa[1] = *(const float4*)(ap + 4);
        } else {
            pa[0] = make_float4(0.f, 0.f, 0.f, 0.f);
            pa[1] = make_float4(0.f, 0.f, 0.f, 0.f);
        }
#pragma unroll
        for (int l = 0; l < 4; ++l)
            pb[l] = *(const float4*)(Wp + (size_t)(col0 + bRow4 + l * 32) * 512 + kt + bK);
    };
    loadT(0);
    for (int kt = 0; kt < 512; kt += 16) {
        __syncthreads();
#pragma unroll
        for (int g = 0; g < 2; ++g) {
            float4 v = pa[g];
            As[(aK + g * 4 + 0) * 68 + aRow] = v.x;
            As[(aK + g * 4 + 1) * 68 + aRow] = v.y;
            As[(aK + g * 4 + 2) * 68 + aRow] = v.z;
            As[(aK + g * 4 + 3) * 68 + aRow] = v.w;
        }
#pragma unroll
        for (int l = 0; l < 4; ++l) {
            int row = bRow4 + l * 32;
            Bs[(bK + 0) * 132 + row] = pb[l].x;
            Bs[(bK + 1) * 132 + row] = pb[l].y;
            Bs[(bK + 2) * 132 + row] = pb[l].z;
            Bs[(bK + 3) * 132 + row] = pb[l].w;
        }
        __syncthreads();
        if (kt + 16 < 512) loadT(kt + 16);
#pragma unroll
        for (int kk = 0; kk < 16; ++kk) {
            float4 a0 = *(const float4*)&As[kk * 68 + ty * 4];
            float4 a1 = *(const float4*)&As[kk * 68 + 32 + ty * 4];
            float4 b0 = *(const float4*)&Bs[kk * 132 + tx * 4];
            float4 b1 = *(const float4*)&Bs[kk * 132 + 64 + tx * 4];
            float av[8] = {a0.x, a0.y, a0.z, a0.w, a1.x, a1.y, a1.z, a1.w};
            float bv[8] = {b0.x, b0.y, b0.z, b0.w, b1.x, b1.y, b1.z, b1.w};
#pragma unroll
            for (int i = 0; i < 8; ++i)
#pragma unroll
                for (int j = 0; j < 8; ++j)
                    acc[i][j] = fmaf(av[i], bv[j], acc[i][j]);
        }
    }
    __syncthreads();   // reuse smem as red[8][128][2] (2048 floats)
#pragma unroll
    for (int jj = 0; jj < 8; ++jj) {
        int colL = (jj < 4) ? (tx * 4 + jj) : (64 + tx * 4 + (jj - 4));
        float s = 0.f, q = 0.f;
#pragma unroll
        for (int i = 0; i < 8; ++i) { float v = acc[i][jj]; s += v; q = fmaf(v, v, q); }
        smem[(ty * 128 + colL) * 2 + 0] = s;
        smem[(ty * 128 + colL) * 2 + 1] = q;
    }
    __syncthreads();
    {
        float ss = 0.f, qq = 0.f;
#pragma unroll
        for (int r = 0; r < 8; ++r) {
            ss += smem[(r * 128 + tid) * 2 + 0];
            qq += smem[(r * 128 + tid) * 2 + 1];
        }
        colpart[((size_t)blockIdx.x * 1536 + nBase + tid) * 2 + 0] = ss;
        colpart[((size_t)blockIdx.x * 1536 + nBase + tid) * 2 + 1] = qq;
    }
    float* outp = out + (size_t)wsel * NTOT;
#pragma unroll
    for (int i = 0; i < 8; ++i) {
        int m = mBase + ((i < 4) ? (ty * 4 + i) : (32 + ty * 4 + (i - 4)));
        if (m < M) {
            *(float4*)(outp + (size_t)m * 512 + col0 + tx * 4) =
                make_float4(acc[i][0], acc[i][1], acc[i][2], acc[i][3]);
            *(float4*)(outp + (size_t)m * 512 + col0 + 64 + tx * 4) =
                make_float4(acc[i][4], acc[i][5], acc[i][6], acc[i][7]);
        }
    }
}

// ---------------------------------------------------------------------------
// Spike-input GEMM: A uchar [M,512]. BM=64,BN=128,BK=16, 8x8 microtile,
// 128 threads. Grid (63,4)=252 blocks. Fused stats.
// ---------------------------------------------------------------------------
__global__ __launch_bounds__(128) void gemm_b_k(
    const unsigned char* __restrict__ A, const float* __restrict__ W,
    float* __restrict__ out, float* __restrict__ colpart, int M)
{
    __shared__ __align__(16) float smem[3200];   // As[16][68] | Bs[16][132]
    float* As = smem;
    float* Bs = smem + 1088;
    int tid = threadIdx.x;
    int mBase = blockIdx.x * 64;
    int col0 = blockIdx.y * 128;
    int ty = tid >> 4, tx = tid & 15;
    int aRow = tid >> 1, aK = (tid & 1) * 8;
    int bRow4 = tid >> 2, bK = (tid & 3) * 4;
    float acc[8][8] = {};
    uchar4 pa[2];
    float4 pb[4];

    auto loadT = [&](int kt) {
        int m = mBase + aRow;
        if (m < M) {
            pa[0] = *(const uchar4*)(A + (size_t)m * 512 + kt + aK);
            pa[1] = *(const uchar4*)(A + (size_t)m * 512 + kt + aK + 4);
        } else {
            pa[0] = make_uchar4(0, 0, 0, 0); pa[1] = make_uchar4(0, 0, 0, 0);
        }
#pragma unroll
        for (int l = 0; l < 4; ++l)
            pb[l] = *(const float4*)(W + (size_t)(col0 + bRow4 + l * 32) * 512 + kt + bK);
    };
    loadT(0);
    for (int kt = 0; kt < 512; kt += 16) {
        __syncthreads();
#pragma unroll
        for (int g = 0; g < 2; ++g) {
            uchar4 v = pa[g];
            As[(aK + g * 4 + 0) * 68 + aRow] = (float)v.x;
            As[(aK + g * 4 + 1) * 68 + aRow] = (float)v.y;
            As[(aK + g * 4 + 2) * 68 + aRow] = (float)v.z;
            As[(aK + g * 4 + 3) * 68 + aRow] = (float)v.w;
        }
#pragma unroll
        for (int l = 0; l < 4; ++l) {
            int row = bRow4 + l * 32;
            Bs[(bK + 0) * 132 + row] = pb[l].x;
            Bs[(bK + 1) * 132 + row] = pb[l].y;
            Bs[(bK + 2) * 132 + row] = pb[l].z;
            Bs[(bK + 3) * 132 + row] = pb[l].w;
        }
        __syncthreads();
        if (kt + 16 < 512) loadT(kt + 16);
#pragma unroll
        for (int kk = 0; kk < 16; ++kk) {
            float4 a0 = *(const float4*)&As[kk * 68 + ty * 4];
            float4 a1 = *(const float4*)&As[kk * 68 + 32 + ty * 4];
            float4 b0 = *(const float4*)&Bs[kk * 132 + tx * 4];
            float4 b1 = *(const float4*)&Bs[kk * 132 + 64 + tx * 4];
            float av[8] = {a0.x, a0.y, a0.z, a0.w, a1.x, a1.y, a1.z, a1.w};
            float bv[8] = {b0.x, b0.y, b0.z, b0.w, b1.x, b1.y, b1.z, b1.w};
#pragma unroll
            for (int i = 0; i < 8; ++i)
#pragma unroll
                for (int j = 0; j < 8; ++j)
                    acc[i][j] = fmaf(av[i], bv[j], acc[i][j]);
        }
    }
    __syncthreads();
#pragma unroll
    for (int jj = 0; jj < 8; ++jj) {
        int colL = (jj < 4) ? (tx * 4 + jj) : (64 + tx * 4 + (jj - 4));
        float s = 0.f, q = 0.f;
#pragma unroll
        for (int i = 0; i < 8; ++i) { float v = acc[i][jj]; s += v; q = fmaf(v, v, q); }
        smem[(ty * 128 + colL) * 2 + 0] = s;
        smem[(ty * 128 + colL) * 2 + 1] = q;
    }
    __syncthreads();
    {
        float ss = 0.f, qq = 0.f;
#pragma unroll
        for (int r = 0; r < 8; ++r) {
            ss += smem[(r * 128 + tid) * 2 + 0];
            qq += smem[(r * 128 + tid) * 2 + 1];
        }
        colpart[((size_t)blockIdx.x * 512 + col0 + tid) * 2 + 0] = ss;
        colpart[((size_t)blockIdx.x * 512 + col0 + tid) * 2 + 1] = qq;
    }
#pragma unroll
    for (int i = 0; i < 8; ++i) {
        int m = mBase + ((i < 4) ? (ty * 4 + i) : (32 + ty * 4 + (i - 4)));
        if (m < M) {
            *(float4*)(out + (size_t)m * 512 + col0 + tx * 4) =
                make_float4(acc[i][0], acc[i][1], acc[i][2], acc[i][3]);
            *(float4*)(out + (size_t)m * 512 + col0 + 64 + tx * 4) =
                make_float4(acc[i][4], acc[i][5], acc[i][6], acc[i][7]);
        }
    }
}

// ---------------------------------------------------------------------------
// Time-segmented BN+LIF with INLINE stats finalize (f64, identical math).
// ---------------------------------------------------------------------------
__global__ __launch_bounds__(256) void lif_seg_k(
    const float* __restrict__ pre, const float* __restrict__ colpart, int CT, int chunks,
    const float* __restrict__ gamma, const float* __restrict__ beta,
    float* __restrict__ outF, unsigned char* __restrict__ outB, int segLen, int warm)
{
    int gid = blockIdx.x * 256 + threadIdx.x;
    int tensor = gid >> 12;
    int bc = gid & 4095;
    int ch = (tensor << 9) | (bc & 511);
    double s = 0.0, s2 = 0.0;
    for (int k = 0; k < chunks; ++k) {
        s  += (double)colpart[((size_t)k * CT + ch) * 2 + 0];
        s2 += (double)colpart[((size_t)k * CT + ch) * 2 + 1];
    }
    double mean = s / 4000.0;
    double var = s2 / 4000.0 - mean * mean;
    double scd = (double)gamma[ch] / sqrt(var + 1e-5);
    float sc = (float)scd;
    float sh = (float)((double)beta[ch] - mean * scd);
    const float* q0 = pre + (size_t)tensor * NTOT + bc;
    float* oF = outF ? outF + (size_t)tensor * NTOT + bc : nullptr;
    unsigned char* oB = outB ? outB + (size_t)tensor * NTOT + bc : nullptr;
    int t0 = blockIdx.y * segLen;
    int twarm = (t0 - warm > 0) ? (t0 - warm) : 0;
    int tend = (t0 + segLen < TT) ? (t0 + segLen) : TT;
    float v = 0.f;
    float b0[8];
#pragma unroll
    for (int j = 0; j < 8; ++j) {
        int tt = twarm + j;
        b0[j] = (tt < tend) ? q0[(size_t)tt * 4096] : 0.f;
    }
    for (int t = twarm; t < tend; t += 8) {
        float n0[8];
#pragma unroll
        for (int j = 0; j < 8; ++j) {
            int tt = t + 8 + j;
            n0[j] = (tt < tend) ? q0[(size_t)tt * 4096] : 0.f;
        }
#pragma unroll
        for (int j = 0; j < 8; ++j) {
            int tc = t + j;
            if (tc >= tend) break;
            float bnx = fmaf(b0[j], sc, sh);
            float h = fmaf(0.5f, v, bnx);
            float sp = (h >= 1.f) ? 1.f : 0.f;
            v = (h >= 1.f) ? 0.f : h;
            if (tc >= t0) {
                if (oB) oB[(size_t)tc * 4096] = (unsigned char)sp;
                else    oF[(size_t)tc * 4096] = sp;
            }
        }
#pragma unroll
        for (int j = 0; j < 8; ++j) b0[j] = n0[j];
    }
}

// ---------------------------------------------------------------------------
// KtV partials over t-quarters from byte spikes (exact integer sums).
// ---------------------------------------------------------------------------
__global__ __launch_bounds__(256) void ktv_part_k(
    const unsigned char* __restrict__ kspk, const unsigned char* __restrict__ vspk,
    float* __restrict__ part)
{
    __shared__ __align__(16) float kb[16][64], vb[16][64];
    int bh = blockIdx.x;
    int seg = blockIdx.y;
    int t0p = seg * 125, t1p = t0p + 125;
    int b = bh >> 3, h = bh & 7;
    int tid = threadIdx.x;
    int d1b = (tid >> 4) * 4, d2b = (tid & 15) * 4;
    size_t cb = (size_t)b * 512 + h * 64;
    int sRow = tid >> 4;
    int sD = (tid & 15) * 4;
    float acc[4][4] = {};
    uchar4 pk, pv;
    auto preload = [&](int tt) {
        int t = tt + sRow;
        if (t < t1p) {
            pk = *(const uchar4*)(kspk + (size_t)t * 4096 + cb + sD);
            pv = *(const uchar4*)(vspk + (size_t)t * 4096 + cb + sD);
        } else {
            pk = make_uchar4(0, 0, 0, 0); pv = make_uchar4(0, 0, 0, 0);
        }
    };
    preload(t0p);
    for (int tt = t0p; tt < t1p; tt += 16) {
        __syncthreads();
        kb[sRow][sD + 0] = (float)pk.x; kb[sRow][sD + 1] = (float)pk.y;
        kb[sRow][sD + 2] = (float)pk.z; kb[sRow][sD + 3] = (float)pk.w;
        vb[sRow][sD + 0] = (float)pv.x; vb[sRow][sD + 1] = (float)pv.y;
        vb[sRow][sD + 2] = (float)pv.z; vb[sRow][sD + 3] = (float)pv.w;
        __syncthreads();
        preload(tt + 16);
#pragma unroll
        for (int tl = 0; tl < 16; ++tl) {
            float4 k4 = *(const float4*)&kb[tl][d1b];
            float4 v4 = *(const float4*)&vb[tl][d2b];
            float ka[4] = {k4.x, k4.y, k4.z, k4.w};
            float va[4] = {v4.x, v4.y, v4.z, v4.w};
#pragma unroll
            for (int i = 0; i < 4; ++i)
#pragma unroll
                for (int j = 0; j < 4; ++j)
                    acc[i][j] = fmaf(ka[i], va[j], acc[i][j]);
        }
    }
    size_t ob = ((size_t)seg * 64 + bh) * 4096;
#pragma unroll
    for (int i = 0; i < 4; ++i)
        *(float4*)(part + ob + (size_t)(d1b + i) * 64 + d2b) =
            make_float4(acc[i][0], acc[i][1], acc[i][2], acc[i][3]);
}

__global__ __launch_bounds__(256) void ktv_reduce_k(
    const float* __restrict__ part, float* __restrict__ ktv)
{
    int i4 = (blockIdx.x * 256 + threadIdx.x) * 4;
    float4 a = *(const float4*)(part + i4);
    float4 b = *(const float4*)(part + 262144 + i4);
    float4 c = *(const float4*)(part + 2 * 262144 + i4);
    float4 d = *(const float4*)(part + 3 * 262144 + i4);
    *(float4*)(ktv + i4) = make_float4(((a.x + b.x) + c.x) + d.x,
                                       ((a.y + b.y) + c.y) + d.y,
                                       ((a.z + b.z) + c.z) + d.z,
                                       ((a.w + b.w) + c.w) + d.w);
}

// ---------------------------------------------------------------------------
// Global attention apply, t-tiled x10.
// ---------------------------------------------------------------------------
__global__ __launch_bounds__(256) void gapply_t_k(
    const unsigned char* __restrict__ sq, const float* __restrict__ ktv,
    float* __restrict__ gpre, float gscale)
{
    __shared__ float qs[10][512];
    int tid = threadIdx.x;
    int t0 = blockIdx.x * 10;
    int b = blockIdx.y;
    for (int i = tid; i < 1280; i += 256) {
        int t = i >> 7;
        int c4 = (i & 127) * 4;
        uchar4 u = *(const uchar4*)(sq + (size_t)(t0 + t) * 4096 + b * 512 + c4);
        qs[t][c4 + 0] = (float)u.x; qs[t][c4 + 1] = (float)u.y;
        qs[t][c4 + 2] = (float)u.z; qs[t][c4 + 3] = (float)u.w;
    }
    __syncthreads();
#pragma unroll
    for (int half = 0; half < 2; ++half) {
        int c = tid + half * 256;
        int h = c >> 6, dcol = c & 63;
        const float* kt = ktv + ((size_t)(b * 8 + h) * 64) * 64 + dcol;
        float acc[10] = {};
        for (int d1 = 0; d1 < 64; ++d1) {
            float kv = kt[(size_t)d1 * 64];
#pragma unroll
            for (int t = 0; t < 10; ++t)
                acc[t] = fmaf(qs[t][h * 64 + d1], kv, acc[t]);
        }
#pragma unroll
        for (int t = 0; t < 10; ++t)
            gpre[(size_t)(t0 + t) * 4096 + b * 512 + c] = acc[t] * gscale;
    }
}

// ---------------------------------------------------------------------------
// Local banded attention; LDS padded to 68 cols.
// ---------------------------------------------------------------------------
__global__ __launch_bounds__(256) void local_k(
    const unsigned char* __restrict__ qspk, const unsigned char* __restrict__ kspk,
    const unsigned char* __restrict__ vspk, float* __restrict__ lpre, float lscale)
{
    __shared__ __align__(16) float qs[32][68];
    __shared__ __align__(16) float ks[72][68];
    __shared__ __align__(16) float vs[72][68];
    __shared__ float sm[32][72];
    int t0 = blockIdx.x * 32;
    int bh = blockIdx.y;
    int b = bh >> 3, h = bh & 7;
    int tid = threadIdx.x;
    size_t cb = (size_t)b * 512 + h * 64;

    for (int i = tid; i < 512; i += 256) {
        int r = i >> 4, d4 = (i & 15) * 4;
        int t = t0 + r;
        if (t < TT) {
            uchar4 u = *(const uchar4*)(qspk + (size_t)t * 4096 + cb + d4);
            qs[r][d4 + 0] = (float)u.x; qs[r][d4 + 1] = (float)u.y;
            qs[r][d4 + 2] = (float)u.z; qs[r][d4 + 3] = (float)u.w;
        } else {
            qs[r][d4 + 0] = 0.f; qs[r][d4 + 1] = 0.f; qs[r][d4 + 2] = 0.f; qs[r][d4 + 3] = 0.f;
        }
    }
    for (int i = tid; i < 1152; i += 256) {
        int r = i >> 4, d4 = (i & 15) * 4;
        int u_ = t0 - WW + r;
        if (u_ >= 0 && u_ < TT) {
            uchar4 uk = *(const uchar4*)(kspk + (size_t)u_ * 4096 + cb + d4);
            uchar4 uv = *(const uchar4*)(vspk + (size_t)u_ * 4096 + cb + d4);
            ks[r][d4 + 0] = (float)uk.x; ks[r][d4 + 1] = (float)uk.y;
            ks[r][d4 + 2] = (float)uk.z; ks[r][d4 + 3] = (float)uk.w;
            vs[r][d4 + 0] = (float)uv.x; vs[r][d4 + 1] = (float)uv.y;
            vs[r][d4 + 2] = (float)uv.z; vs[r][d4 + 3] = (float)uv.w;
        } else {
            ks[r][d4 + 0] = 0.f; ks[r][d4 + 1] = 0.f; ks[r][d4 + 2] = 0.f; ks[r][d4 + 3] = 0.f;
            vs[r][d4 + 0] = 0.f; vs[r][d4 + 1] = 0.f; vs[r][d4 + 2] = 0.f; vs[r][d4 + 3] = 0.f;
        }
    }
    __syncthreads();

    int tA = tid >> 3;
    int ug = tid & 7;
    float4 qreg[16];
#pragma unroll
    for (int i = 0; i < 16; ++i) qreg[i] = *(const float4*)&qs[tA][i * 4];
#pragma unroll
    for (int ui = 0; ui < 9; ++ui) {
        int u = ug + ui * 8;
        float acc = 0.f;
#pragma unroll
        for (int i = 0; i < 16; ++i) {
            float4 k4 = *(const float4*)&ks[u][i * 4];
            acc = fmaf(qreg[i].x, k4.x, acc);
            acc = fmaf(qreg[i].y, k4.y, acc);
            acc = fmaf(qreg[i].z, k4.z, acc);
            acc = fmaf(qreg[i].w, k4.w, acc);
        }
        sm[tA][u] = acc;
    }
    __syncthreads();

#pragma unroll
    for (int oi = 0; oi < 2; ++oi) {
        int idx = tid + oi * 256;
        int t = idx >> 4;
        int dg = (idx & 15) * 4;
        float4 acc = make_float4(0.f, 0.f, 0.f, 0.f);
        for (int o = 0; o < 41; ++o) {
            int u = t + o;
            float s = sm[t][u];
            float4 v4 = *(const float4*)&vs[u][dg];
            acc.x = fmaf(s, v4.x, acc.x);
            acc.y = fmaf(s, v4.y, acc.y);
            acc.z = fmaf(s, v4.z, acc.z);
            acc.w = fmaf(s, v4.w, acc.w);
        }
        int tg = t0 + t;
        if (tg < TT) {
            acc.x *= lscale; acc.y *= lscale; acc.z *= lscale; acc.w *= lscale;
            *(float4*)(lpre + (size_t)tg * 4096 + cb + dg) = acc;
        }
    }
}

// ---------------------------------------------------------------------------
// Fused branch kernel: g-LIF + l-LIF + dwconv9-LIF + head-mix (wave shfl) +
// y0-LIF.
// ---------------------------------------------------------------------------
__global__ __launch_bounds__(256) void branch_y0_k(
    const float* __restrict__ gpre, const float* __restrict__ lpre,
    const unsigned char* __restrict__ sv, const float* __restrict__ wdw,
    const float* __restrict__ wpw, unsigned char* __restrict__ sy0,
    int segLen, int warm)
{
    int tid = threadIdx.x;
    int wave = tid >> 6, lane = tid & 63;
    int gw = blockIdx.x * 4 + wave;    // 0..63
    int b = gw >> 3, dg = gw & 7;
    int h = lane >> 3, dl = lane & 7;
    int c = h * 64 + dg * 8 + dl;
    int base = b * 512 + c;
    float w9[9];
#pragma unroll
    for (int j = 0; j < 9; ++j) w9[j] = wdw[h * 9 + j];
    float w8[8];
#pragma unroll
    for (int j = 0; j < 8; ++j) w8[j] = wpw[h * 8 + j];
    int t0 = blockIdx.y * segLen;
    int twarm = (t0 - warm > 0) ? (t0 - warm) : 0;
    int tend = (t0 + segLen < TT) ? (t0 + segLen) : TT;
    float vg = 0.f, vl = 0.f, vd = 0.f, vy = 0.f;
    float win[12];
#pragma unroll
    for (int i = 0; i < 12; ++i) {
        int tt = twarm - 4 + i;
        win[i] = (tt >= 0 && tt < TT) ? (float)sv[(size_t)tt * 4096 + base] : 0.f;
    }
    float pg[4], pl[4], pv[4];
    auto pref = [&](int t) {
#pragma unroll
        for (int j = 0; j < 4; ++j) {
            int tt = t + j;
            bool in = tt < tend;
            pg[j] = in ? gpre[(size_t)tt * 4096 + base] : 0.f;
            pl[j] = in ? lpre[(size_t)tt * 4096 + base] : 0.f;
            int tv = t + 8 + j;
            pv[j] = (tv < TT) ? (float)sv[(size_t)tv * 4096 + base] : 0.f;
        }
    };
    pref(twarm);
    for (int t = twarm; t < tend; t += 4) {
        float cg[4], cl[4], cv[4];
#pragma unroll
        for (int j = 0; j < 4; ++j) { cg[j] = pg[j]; cl[j] = pl[j]; cv[j] = pv[j]; }
        pref(t + 4);
#pragma unroll
        for (int j = 0; j < 4; ++j) {
            int tc = t + j;
            if (tc >= tend) break;
            float x = 0.f;
#pragma unroll
            for (int q = 0; q < 9; ++q) x = fmaf(w9[q], win[j + q], x);
            float hd = fmaf(0.5f, vd, x);
            float sd = (hd >= 1.f) ? 1.f : 0.f;
            vd = (hd >= 1.f) ? 0.f : hd;
            float hg = fmaf(0.5f, vg, cg[j]);
            float sg = (hg >= 1.f) ? 1.f : 0.f;
            vg = (hg >= 1.f) ? 0.f : hg;
            float hl = fmaf(0.5f, vl, cl[j]);
            float sl = (hl >= 1.f) ? 1.f : 0.f;
            vl = (hl >= 1.f) ? 0.f : hl;
            float mix = 0.f;
#pragma unroll
            for (int h2 = 0; h2 < 8; ++h2)
                mix = fmaf(w8[h2], __shfl(sd, h2 * 8 + dl, 64), mix);
            float xy = (sg + sl) + mix;
            float hy = fmaf(0.5f, vy, xy);
            float sy = (hy >= 1.f) ? 1.f : 0.f;
            vy = (hy >= 1.f) ? 0.f : hy;
            if (tc >= t0) sy0[(size_t)tc * 4096 + base] = (unsigned char)sy;
        }
#pragma unroll
        for (int i = 0; i < 8; ++i) win[i] = win[i + 4];
#pragma unroll
        for (int i = 0; i < 4; ++i) win[8 + i] = cv[i];
    }
}

// ---------------------------------------------------------------------------
extern "C" void kernel_launch(void* const* d_in, const int* in_sizes, int n_in,
                              void* d_out, int out_size, void* d_ws, size_t ws_size,
                              hipStream_t stream)
{
    const float* x       = (const float*)d_in[0];
    const float* wq      = (const float*)d_in[1];
    const float* wk      = (const float*)d_in[2];
    const float* wv      = (const float*)d_in[3];
    const float* w_mattn = (const float*)d_in[4];
    const float* w_proj  = (const float*)d_in[5];
    const float* w_dw    = (const float*)d_in[6];
    const float* w_pw    = (const float*)d_in[7];
    const float* bn_g    = (const float*)d_in[8];
    const float* bn_b    = (const float*)d_in[9];
    float* out = (float*)d_out;
    float* ws = (float*)d_ws;

    float gs32 = (float)std::sqrt((double)(64 * 500));
    float gscale = (float)(1.0 / (double)gs32);
    float ls32 = (float)std::sqrt((double)(64 * 41));
    float lscale = (float)(1.0 / (double)ls32);
    const int M = TT * 8;   // 4000

    float* S0 = ws;
    float* S1 = ws + (size_t)NTOT;
    float* S2 = ws + 2 * (size_t)NTOT;
    float* part4   = ws + 3 * (size_t)NTOT;     // 4*262144
    float* ktvBuf  = part4 + 4 * 262144;        // 262144
    float* colpart = ktvBuf + 262144;           // 196608 (63 chunks * 1536 * 2)
    unsigned char* spk = (unsigned char*)(colpart + 196608);
    unsigned char* sq  = spk;
    unsigned char* sk  = spk + (size_t)NTOT;
    unsigned char* sv  = spk + 2 * (size_t)NTOT;
    unsigned char* sy0 = spk + 3 * (size_t)NTOT;
    unsigned char* sy1 = spk + 4 * (size_t)NTOT;

    // 1) QKV GEMM (fused column stats, 756 x 2-wave blocks, all resident)
    gemm_f_k<<<dim3(63, 12), 128, 0, stream>>>(x, wq, wk, wv, S0, colpart, M);
    // 2) segmented BN+LIF (inline stats finalize, 63 chunks) -> q,k,v byte spikes
    lif_seg_k<<<dim3(48, 5), 256, 0, stream>>>(S0, colpart, 1536, 63, bn_g, bn_b,
                                               nullptr, sq, 100, 64);
    // 3) global branch
    ktv_part_k<<<dim3(64, 4), 256, 0, stream>>>(sk, sv, part4);
    ktv_reduce_k<<<256, 256, 0, stream>>>(part4, ktvBuf);
    gapply_t_k<<<dim3(50, 8), 256, 0, stream>>>(sq, ktvBuf, S0, gscale);      // g_pre -> S0
    // 4) local branch -> l_pre S1
    local_k<<<dim3(16, 64), 256, 0, stream>>>(sq, sk, sv, S1, lscale);
    // 5) fused g/l/dw LIFs + mix + y0 LIF -> sy0 bytes
    branch_y0_k<<<dim3(16, 10), 256, 0, stream>>>(S0, S1, sv, w_dw, w_pw, sy0, 50, 64);
    // 6) mattn GEMM (byte A, fused stats) -> S2; LIF -> sy1 bytes
    gemm_b_k<<<dim3(63, 4), 128, 0, stream>>>(sy0, w_mattn, S2, colpart, M);
    lif_seg_k<<<dim3(16, 10), 256, 0, stream>>>(S2, colpart, 512, 63, bn_g + 1536,
                                                bn_b + 1536, nullptr, sy1, 50, 64);
    // 7) proj GEMM -> S0; LIF -> out (fp32)
    gemm_b_k<<<dim3(63, 4), 128, 0, stream>>>(sy1, w_proj, S0, colpart, M);
    lif_seg_k<<<dim3(16, 10), 256, 0, stream>>>(S0, colpart, 512, 63, bn_g + 2048,
                                                bn_b + 2048, out, nullptr, 50, 64);

    (void)in_sizes; (void)n_in; (void)out_size; (void)ws_size;
}

// Round 9
// 433.101 us; speedup vs baseline: 1.0877x; 1.0877x over previous
//
#include <hip/hip_runtime.h>
#include <cmath>

#define TT 500
#define NTOT 2048000       // T*B*C elements
#define WW 20

// ---------------------------------------------------------------------------
// QKV GEMM: A fp32 [M,512], 3 weights. BM=64,BN=128,BK=32, 4x8 microtile,
// 256 threads. 1D grid 768 with XCD swizzle: xcd=bid&7 owns m-stripes
// [8*xcd, 8*xcd+8) -> per-XCD A footprint 1 MB (L2-resident), all n-blocks
// of a stripe on one XCD. m=63 blocks compute zeros (exact, stats chunk 63=0).
// ---------------------------------------------------------------------------
__global__ __launch_bounds__(256) void gemm_f_k(
    const float* __restrict__ A,
    const float* __restrict__ W0, const float* __restrict__ W1, const float* __restrict__ W2,
    float* __restrict__ out, float* __restrict__ colpart, int M)
{
    __shared__ __align__(16) float smem[6400];   // As[32][68] | Bs[32][132]; red aliases
    float* As = smem;
    float* Bs = smem + 2176;
    int tid = threadIdx.x;
    int bid = blockIdx.x;
    int xcd = bid & 7;
    int j = bid >> 3;                 // 0..95
    int mblk = (xcd << 3) | (j & 7);  // 0..63
    int nblk = j >> 3;                // 0..11
    int mBase = mblk * 64;
    int nBase = nblk * 128;
    int wsel = nBase >> 9;
    const float* Wp = (wsel == 0) ? W0 : ((wsel == 1) ? W1 : W2);
    int col0 = nBase & 511;
    int ty = tid >> 4, tx = tid & 15;
    int ldRow = tid >> 2;          // 0..63
    int ldK = (tid & 3) * 4;       // 0,4,8,12
    float acc[4][8] = {};
    float4 pa[2], pb[2][2];

    auto loadT = [&](int kt) {
        int m = mBase + ldRow;
        if (m < M) {
            const float* ap = A + (size_t)m * 512 + kt + ldK;
            pa[0] = *(const float4*)ap;
            pa[1] = *(const float4*)(ap + 16);
        } else {
            pa[0] = make_float4(0.f, 0.f, 0.f, 0.f);
            pa[1] = make_float4(0.f, 0.f, 0.f, 0.f);
        }
#pragma unroll
        for (int l = 0; l < 2; ++l) {
            const float* bp = Wp + (size_t)(col0 + ldRow + l * 64) * 512 + kt + ldK;
            pb[l][0] = *(const float4*)bp;
            pb[l][1] = *(const float4*)(bp + 16);
        }
    };
    loadT(0);
    for (int kt = 0; kt < 512; kt += 32) {
        __syncthreads();
#pragma unroll
        for (int g = 0; g < 2; ++g) {
            As[(ldK + 16 * g + 0) * 68 + ldRow] = pa[g].x;
            As[(ldK + 16 * g + 1) * 68 + ldRow] = pa[g].y;
            As[(ldK + 16 * g + 2) * 68 + ldRow] = pa[g].z;
            As[(ldK + 16 * g + 3) * 68 + ldRow] = pa[g].w;
        }
#pragma unroll
        for (int l = 0; l < 2; ++l)
#pragma unroll
            for (int g = 0; g < 2; ++g) {
                int row = ldRow + l * 64;
                Bs[(ldK + 16 * g + 0) * 132 + row] = pb[l][g].x;
                Bs[(ldK + 16 * g + 1) * 132 + row] = pb[l][g].y;
                Bs[(ldK + 16 * g + 2) * 132 + row] = pb[l][g].z;
                Bs[(ldK + 16 * g + 3) * 132 + row] = pb[l][g].w;
            }
        __syncthreads();
        if (kt + 32 < 512) loadT(kt + 32);
#pragma unroll
        for (int kk = 0; kk < 32; ++kk) {
            float4 a0 = *(const float4*)&As[kk * 68 + ty * 4];
            float4 b0 = *(const float4*)&Bs[kk * 132 + tx * 4];
            float4 b1 = *(const float4*)&Bs[kk * 132 + 64 + tx * 4];
            float av[4] = {a0.x, a0.y, a0.z, a0.w};
            float bv[8] = {b0.x, b0.y, b0.z, b0.w, b1.x, b1.y, b1.z, b1.w};
#pragma unroll
            for (int i = 0; i < 4; ++i)
#pragma unroll
                for (int jj = 0; jj < 8; ++jj)
                    acc[i][jj] = fmaf(av[i], bv[jj], acc[i][jj]);
        }
    }
    __syncthreads();   // reuse smem as red[16][128][2]
#pragma unroll
    for (int jj = 0; jj < 8; ++jj) {
        int colL = (jj < 4) ? (tx * 4 + jj) : (64 + tx * 4 + (jj - 4));
        float s = 0.f, q = 0.f;
#pragma unroll
        for (int i = 0; i < 4; ++i) { float v = acc[i][jj]; s += v; q = fmaf(v, v, q); }
        smem[(ty * 128 + colL) * 2 + 0] = s;
        smem[(ty * 128 + colL) * 2 + 1] = q;
    }
    __syncthreads();
    if (tid < 128) {
        float ss = 0.f, qq = 0.f;
#pragma unroll
        for (int r = 0; r < 16; ++r) {
            ss += smem[(r * 128 + tid) * 2 + 0];
            qq += smem[(r * 128 + tid) * 2 + 1];
        }
        colpart[((size_t)mblk * 1536 + nBase + tid) * 2 + 0] = ss;
        colpart[((size_t)mblk * 1536 + nBase + tid) * 2 + 1] = qq;
    }
    float* outp = out + (size_t)wsel * NTOT;
#pragma unroll
    for (int i = 0; i < 4; ++i) {
        int m = mBase + ty * 4 + i;
        if (m < M) {
            *(float4*)(outp + (size_t)m * 512 + col0 + tx * 4) =
                make_float4(acc[i][0], acc[i][1], acc[i][2], acc[i][3]);
            *(float4*)(outp + (size_t)m * 512 + col0 + 64 + tx * 4) =
                make_float4(acc[i][4], acc[i][5], acc[i][6], acc[i][7]);
        }
    }
}

// ---------------------------------------------------------------------------
// Spike-input GEMM: A uchar [M,512], one weight. BM=64,BN=128,BK=32, 4x8,
// 256 threads. 1D grid 256 (XCD-swizzled) = exactly 1 block/CU, single pass.
// ---------------------------------------------------------------------------
__global__ __launch_bounds__(256) void gemm_b_k(
    const unsigned char* __restrict__ A, const float* __restrict__ W,
    float* __restrict__ out, float* __restrict__ colpart, int M)
{
    __shared__ __align__(16) float smem[6400];   // As[32][68] | Bs[32][132]
    float* As = smem;
    float* Bs = smem + 2176;
    int tid = threadIdx.x;
    int bid = blockIdx.x;
    int xcd = bid & 7;
    int j = bid >> 3;                 // 0..31
    int mblk = (xcd << 3) | (j & 7);  // 0..63
    int nblk = j >> 3;                // 0..3
    int mBase = mblk * 64;
    int col0 = nblk * 128;
    int ty = tid >> 4, tx = tid & 15;
    int ldRow = tid >> 2;
    int ldK = (tid & 3) * 4;
    float acc[4][8] = {};
    uchar4 pa[2];
    float4 pb[2][2];

    auto loadT = [&](int kt) {
        int m = mBase + ldRow;
        if (m < M) {
            pa[0] = *(const uchar4*)(A + (size_t)m * 512 + kt + ldK);
            pa[1] = *(const uchar4*)(A + (size_t)m * 512 + kt + 16 + ldK);
        } else {
            pa[0] = make_uchar4(0, 0, 0, 0); pa[1] = make_uchar4(0, 0, 0, 0);
        }
#pragma unroll
        for (int l = 0; l < 2; ++l) {
            const float* bp = W + (size_t)(col0 + ldRow + l * 64) * 512 + kt + ldK;
            pb[l][0] = *(const float4*)bp;
            pb[l][1] = *(const float4*)(bp + 16);
        }
    };
    loadT(0);
    for (int kt = 0; kt < 512; kt += 32) {
        __syncthreads();
#pragma unroll
        for (int g = 0; g < 2; ++g) {
            As[(ldK + 16 * g + 0) * 68 + ldRow] = (float)pa[g].x;
            As[(ldK + 16 * g + 1) * 68 + ldRow] = (float)pa[g].y;
            As[(ldK + 16 * g + 2) * 68 + ldRow] = (float)pa[g].z;
            As[(ldK + 16 * g + 3) * 68 + ldRow] = (float)pa[g].w;
        }
#pragma unroll
        for (int l = 0; l < 2; ++l)
#pragma unroll
            for (int g = 0; g < 2; ++g) {
                int row = ldRow + l * 64;
                Bs[(ldK + 16 * g + 0) * 132 + row] = pb[l][g].x;
                Bs[(ldK + 16 * g + 1) * 132 + row] = pb[l][g].y;
                Bs[(ldK + 16 * g + 2) * 132 + row] = pb[l][g].z;
                Bs[(ldK + 16 * g + 3) * 132 + row] = pb[l][g].w;
            }
        __syncthreads();
        if (kt + 32 < 512) loadT(kt + 32);
#pragma unroll
        for (int kk = 0; kk < 32; ++kk) {
            float4 a0 = *(const float4*)&As[kk * 68 + ty * 4];
            float4 b0 = *(const float4*)&Bs[kk * 132 + tx * 4];
            float4 b1 = *(const float4*)&Bs[kk * 132 + 64 + tx * 4];
            float av[4] = {a0.x, a0.y, a0.z, a0.w};
            float bv[8] = {b0.x, b0.y, b0.z, b0.w, b1.x, b1.y, b1.z, b1.w};
#pragma unroll
            for (int i = 0; i < 4; ++i)
#pragma unroll
                for (int jj = 0; jj < 8; ++jj)
                    acc[i][jj] = fmaf(av[i], bv[jj], acc[i][jj]);
        }
    }
    __syncthreads();
#pragma unroll
    for (int jj = 0; jj < 8; ++jj) {
        int colL = (jj < 4) ? (tx * 4 + jj) : (64 + tx * 4 + (jj - 4));
        float s = 0.f, q = 0.f;
#pragma unroll
        for (int i = 0; i < 4; ++i) { float v = acc[i][jj]; s += v; q = fmaf(v, v, q); }
        smem[(ty * 128 + colL) * 2 + 0] = s;
        smem[(ty * 128 + colL) * 2 + 1] = q;
    }
    __syncthreads();
    if (tid < 128) {
        float ss = 0.f, qq = 0.f;
#pragma unroll
        for (int r = 0; r < 16; ++r) {
            ss += smem[(r * 128 + tid) * 2 + 0];
            qq += smem[(r * 128 + tid) * 2 + 1];
        }
        colpart[((size_t)mblk * 512 + col0 + tid) * 2 + 0] = ss;
        colpart[((size_t)mblk * 512 + col0 + tid) * 2 + 1] = qq;
    }
#pragma unroll
    for (int i = 0; i < 4; ++i) {
        int m = mBase + ty * 4 + i;
        if (m < M) {
            *(float4*)(out + (size_t)m * 512 + col0 + tx * 4) =
                make_float4(acc[i][0], acc[i][1], acc[i][2], acc[i][3]);
            *(float4*)(out + (size_t)m * 512 + col0 + 64 + tx * 4) =
                make_float4(acc[i][4], acc[i][5], acc[i][6], acc[i][7]);
        }
    }
}

// ---------------------------------------------------------------------------
// Time-segmented BN+LIF with INLINE stats finalize (f64, identical math).
// ---------------------------------------------------------------------------
__global__ __launch_bounds__(256) void lif_seg_k(
    const float* __restrict__ pre, const float* __restrict__ colpart, int CT, int chunks,
    const float* __restrict__ gamma, const float* __restrict__ beta,
    float* __restrict__ outF, unsigned char* __restrict__ outB, int segLen, int warm)
{
    int gid = blockIdx.x * 256 + threadIdx.x;
    int tensor = gid >> 12;
    int bc = gid & 4095;
    int ch = (tensor << 9) | (bc & 511);
    double s = 0.0, s2 = 0.0;
    for (int k = 0; k < chunks; ++k) {
        s  += (double)colpart[((size_t)k * CT + ch) * 2 + 0];
        s2 += (double)colpart[((size_t)k * CT + ch) * 2 + 1];
    }
    double mean = s / 4000.0;
    double var = s2 / 4000.0 - mean * mean;
    double scd = (double)gamma[ch] / sqrt(var + 1e-5);
    float sc = (float)scd;
    float sh = (float)((double)beta[ch] - mean * scd);
    const float* q0 = pre + (size_t)tensor * NTOT + bc;
    float* oF = outF ? outF + (size_t)tensor * NTOT + bc : nullptr;
    unsigned char* oB = outB ? outB + (size_t)tensor * NTOT + bc : nullptr;
    int t0 = blockIdx.y * segLen;
    int twarm = (t0 - warm > 0) ? (t0 - warm) : 0;
    int tend = (t0 + segLen < TT) ? (t0 + segLen) : TT;
    float v = 0.f;
    float b0[8];
#pragma unroll
    for (int j = 0; j < 8; ++j) {
        int tt = twarm + j;
        b0[j] = (tt < tend) ? q0[(size_t)tt * 4096] : 0.f;
    }
    for (int t = twarm; t < tend; t += 8) {
        float n0[8];
#pragma unroll
        for (int j = 0; j < 8; ++j) {
            int tt = t + 8 + j;
            n0[j] = (tt < tend) ? q0[(size_t)tt * 4096] : 0.f;
        }
#pragma unroll
        for (int j = 0; j < 8; ++j) {
            int tc = t + j;
            if (tc >= tend) break;
            float bnx = fmaf(b0[j], sc, sh);
            float h = fmaf(0.5f, v, bnx);
            float sp = (h >= 1.f) ? 1.f : 0.f;
            v = (h >= 1.f) ? 0.f : h;
            if (tc >= t0) {
                if (oB) oB[(size_t)tc * 4096] = (unsigned char)sp;
                else    oF[(size_t)tc * 4096] = sp;
            }
        }
#pragma unroll
        for (int j = 0; j < 8; ++j) b0[j] = n0[j];
    }
}

// ---------------------------------------------------------------------------
// KtV partials over t-quarters from byte spikes (exact integer sums).
// ---------------------------------------------------------------------------
__global__ __launch_bounds__(256) void ktv_part_k(
    const unsigned char* __restrict__ kspk, const unsigned char* __restrict__ vspk,
    float* __restrict__ part)
{
    __shared__ __align__(16) float kb[16][64], vb[16][64];
    int bh = blockIdx.x;
    int seg = blockIdx.y;
    int t0p = seg * 125, t1p = t0p + 125;
    int b = bh >> 3, h = bh & 7;
    int tid = threadIdx.x;
    int d1b = (tid >> 4) * 4, d2b = (tid & 15) * 4;
    size_t cb = (size_t)b * 512 + h * 64;
    int sRow = tid >> 4;
    int sD = (tid & 15) * 4;
    float acc[4][4] = {};
    uchar4 pk, pv;
    auto preload = [&](int tt) {
        int t = tt + sRow;
        if (t < t1p) {
            pk = *(const uchar4*)(kspk + (size_t)t * 4096 + cb + sD);
            pv = *(const uchar4*)(vspk + (size_t)t * 4096 + cb + sD);
        } else {
            pk = make_uchar4(0, 0, 0, 0); pv = make_uchar4(0, 0, 0, 0);
        }
    };
    preload(t0p);
    for (int tt = t0p; tt < t1p; tt += 16) {
        __syncthreads();
        kb[sRow][sD + 0] = (float)pk.x; kb[sRow][sD + 1] = (float)pk.y;
        kb[sRow][sD + 2] = (float)pk.z; kb[sRow][sD + 3] = (float)pk.w;
        vb[sRow][sD + 0] = (float)pv.x; vb[sRow][sD + 1] = (float)pv.y;
        vb[sRow][sD + 2] = (float)pv.z; vb[sRow][sD + 3] = (float)pv.w;
        __syncthreads();
        preload(tt + 16);
#pragma unroll
        for (int tl = 0; tl < 16; ++tl) {
            float4 k4 = *(const float4*)&kb[tl][d1b];
            float4 v4 = *(const float4*)&vb[tl][d2b];
            float ka[4] = {k4.x, k4.y, k4.z, k4.w};
            float va[4] = {v4.x, v4.y, v4.z, v4.w};
#pragma unroll
            for (int i = 0; i < 4; ++i)
#pragma unroll
                for (int j = 0; j < 4; ++j)
                    acc[i][j] = fmaf(ka[i], va[j], acc[i][j]);
        }
    }
    size_t ob = ((size_t)seg * 64 + bh) * 4096;
#pragma unroll
    for (int i = 0; i < 4; ++i)
        *(float4*)(part + ob + (size_t)(d1b + i) * 64 + d2b) =
            make_float4(acc[i][0], acc[i][1], acc[i][2], acc[i][3]);
}

__global__ __launch_bounds__(256) void ktv_reduce_k(
    const float* __restrict__ part, float* __restrict__ ktv)
{
    int i4 = (blockIdx.x * 256 + threadIdx.x) * 4;
    float4 a = *(const float4*)(part + i4);
    float4 b = *(const float4*)(part + 262144 + i4);
    float4 c = *(const float4*)(part + 2 * 262144 + i4);
    float4 d = *(const float4*)(part + 3 * 262144 + i4);
    *(float4*)(ktv + i4) = make_float4(((a.x + b.x) + c.x) + d.x,
                                       ((a.y + b.y) + c.y) + d.y,
                                       ((a.z + b.z) + c.z) + d.z,
                                       ((a.w + b.w) + c.w) + d.w);
}

// ---------------------------------------------------------------------------
// Global attention apply, t-tiled x10.
// ---------------------------------------------------------------------------
__global__ __launch_bounds__(256) void gapply_t_k(
    const unsigned char* __restrict__ sq, const float* __restrict__ ktv,
    float* __restrict__ gpre, float gscale)
{
    __shared__ float qs[10][512];
    int tid = threadIdx.x;
    int t0 = blockIdx.x * 10;
    int b = blockIdx.y;
    for (int i = tid; i < 1280; i += 256) {
        int t = i >> 7;
        int c4 = (i & 127) * 4;
        uchar4 u = *(const uchar4*)(sq + (size_t)(t0 + t) * 4096 + b * 512 + c4);
        qs[t][c4 + 0] = (float)u.x; qs[t][c4 + 1] = (float)u.y;
        qs[t][c4 + 2] = (float)u.z; qs[t][c4 + 3] = (float)u.w;
    }
    __syncthreads();
#pragma unroll
    for (int half = 0; half < 2; ++half) {
        int c = tid + half * 256;
        int h = c >> 6, dcol = c & 63;
        const float* kt = ktv + ((size_t)(b * 8 + h) * 64) * 64 + dcol;
        float acc[10] = {};
        for (int d1 = 0; d1 < 64; ++d1) {
            float kv = kt[(size_t)d1 * 64];
#pragma unroll
            for (int t = 0; t < 10; ++t)
                acc[t] = fmaf(qs[t][h * 64 + d1], kv, acc[t]);
        }
#pragma unroll
        for (int t = 0; t < 10; ++t)
            gpre[(size_t)(t0 + t) * 4096 + b * 512 + c] = acc[t] * gscale;
    }
}

// ---------------------------------------------------------------------------
// Local banded attention; LDS padded to 68 cols.
// ---------------------------------------------------------------------------
__global__ __launch_bounds__(256) void local_k(
    const unsigned char* __restrict__ qspk, const unsigned char* __restrict__ kspk,
    const unsigned char* __restrict__ vspk, float* __restrict__ lpre, float lscale)
{
    __shared__ __align__(16) float qs[32][68];
    __shared__ __align__(16) float ks[72][68];
    __shared__ __align__(16) float vs[72][68];
    __shared__ float sm[32][72];
    int t0 = blockIdx.x * 32;
    int bh = blockIdx.y;
    int b = bh >> 3, h = bh & 7;
    int tid = threadIdx.x;
    size_t cb = (size_t)b * 512 + h * 64;

    for (int i = tid; i < 512; i += 256) {
        int r = i >> 4, d4 = (i & 15) * 4;
        int t = t0 + r;
        if (t < TT) {
            uchar4 u = *(const uchar4*)(qspk + (size_t)t * 4096 + cb + d4);
            qs[r][d4 + 0] = (float)u.x; qs[r][d4 + 1] = (float)u.y;
            qs[r][d4 + 2] = (float)u.z; qs[r][d4 + 3] = (float)u.w;
        } else {
            qs[r][d4 + 0] = 0.f; qs[r][d4 + 1] = 0.f; qs[r][d4 + 2] = 0.f; qs[r][d4 + 3] = 0.f;
        }
    }
    for (int i = tid; i < 1152; i += 256) {
        int r = i >> 4, d4 = (i & 15) * 4;
        int u_ = t0 - WW + r;
        if (u_ >= 0 && u_ < TT) {
            uchar4 uk = *(const uchar4*)(kspk + (size_t)u_ * 4096 + cb + d4);
            uchar4 uv = *(const uchar4*)(vspk + (size_t)u_ * 4096 + cb + d4);
            ks[r][d4 + 0] = (float)uk.x; ks[r][d4 + 1] = (float)uk.y;
            ks[r][d4 + 2] = (float)uk.z; ks[r][d4 + 3] = (float)uk.w;
            vs[r][d4 + 0] = (float)uv.x; vs[r][d4 + 1] = (float)uv.y;
            vs[r][d4 + 2] = (float)uv.z; vs[r][d4 + 3] = (float)uv.w;
        } else {
            ks[r][d4 + 0] = 0.f; ks[r][d4 + 1] = 0.f; ks[r][d4 + 2] = 0.f; ks[r][d4 + 3] = 0.f;
            vs[r][d4 + 0] = 0.f; vs[r][d4 + 1] = 0.f; vs[r][d4 + 2] = 0.f; vs[r][d4 + 3] = 0.f;
        }
    }
    __syncthreads();

    int tA = tid >> 3;
    int ug = tid & 7;
    float4 qreg[16];
#pragma unroll
    for (int i = 0; i < 16; ++i) qreg[i] = *(const float4*)&qs[tA][i * 4];
#pragma unroll
    for (int ui = 0; ui < 9; ++ui) {
        int u = ug + ui * 8;
        float acc = 0.f;
#pragma unroll
        for (int i = 0; i < 16; ++i) {
            float4 k4 = *(const float4*)&ks[u][i * 4];
            acc = fmaf(qreg[i].x, k4.x, acc);
            acc = fmaf(qreg[i].y, k4.y, acc);
            acc = fmaf(qreg[i].z, k4.z, acc);
            acc = fmaf(qreg[i].w, k4.w, acc);
        }
        sm[tA][u] = acc;
    }
    __syncthreads();

#pragma unroll
    for (int oi = 0; oi < 2; ++oi) {
        int idx = tid + oi * 256;
        int t = idx >> 4;
        int dg = (idx & 15) * 4;
        float4 acc = make_float4(0.f, 0.f, 0.f, 0.f);
        for (int o = 0; o < 41; ++o) {
            int u = t + o;
            float s = sm[t][u];
            float4 v4 = *(const float4*)&vs[u][dg];
            acc.x = fmaf(s, v4.x, acc.x);
            acc.y = fmaf(s, v4.y, acc.y);
            acc.z = fmaf(s, v4.z, acc.z);
            acc.w = fmaf(s, v4.w, acc.w);
        }
        int tg = t0 + t;
        if (tg < TT) {
            acc.x *= lscale; acc.y *= lscale; acc.z *= lscale; acc.w *= lscale;
            *(float4*)(lpre + (size_t)tg * 4096 + cb + dg) = acc;
        }
    }
}

// ---------------------------------------------------------------------------
// Fused branch kernel: g-LIF + l-LIF + dwconv9-LIF + head-mix (wave shfl) +
// y0-LIF.
// ---------------------------------------------------------------------------
__global__ __launch_bounds__(256) void branch_y0_k(
    const float* __restrict__ gpre, const float* __restrict__ lpre,
    const unsigned char* __restrict__ sv, const float* __restrict__ wdw,
    const float* __restrict__ wpw, unsigned char* __restrict__ sy0,
    int segLen, int warm)
{
    int tid = threadIdx.x;
    int wave = tid >> 6, lane = tid & 63;
    int gw = blockIdx.x * 4 + wave;    // 0..63
    int b = gw >> 3, dg = gw & 7;
    int h = lane >> 3, dl = lane & 7;
    int c = h * 64 + dg * 8 + dl;
    int base = b * 512 + c;
    float w9[9];
#pragma unroll
    for (int j = 0; j < 9; ++j) w9[j] = wdw[h * 9 + j];
    float w8[8];
#pragma unroll
    for (int j = 0; j < 8; ++j) w8[j] = wpw[h * 8 + j];
    int t0 = blockIdx.y * segLen;
    int twarm = (t0 - warm > 0) ? (t0 - warm) : 0;
    int tend = (t0 + segLen < TT) ? (t0 + segLen) : TT;
    float vg = 0.f, vl = 0.f, vd = 0.f, vy = 0.f;
    float win[12];
#pragma unroll
    for (int i = 0; i < 12; ++i) {
        int tt = twarm - 4 + i;
        win[i] = (tt >= 0 && tt < TT) ? (float)sv[(size_t)tt * 4096 + base] : 0.f;
    }
    float pg[4], pl[4], pv[4];
    auto pref = [&](int t) {
#pragma unroll
        for (int j = 0; j < 4; ++j) {
            int tt = t + j;
            bool in = tt < tend;
            pg[j] = in ? gpre[(size_t)tt * 4096 + base] : 0.f;
            pl[j] = in ? lpre[(size_t)tt * 4096 + base] : 0.f;
            int tv = t + 8 + j;
            pv[j] = (tv < TT) ? (float)sv[(size_t)tv * 4096 + base] : 0.f;
        }
    };
    pref(twarm);
    for (int t = twarm; t < tend; t += 4) {
        float cg[4], cl[4], cv[4];
#pragma unroll
        for (int j = 0; j < 4; ++j) { cg[j] = pg[j]; cl[j] = pl[j]; cv[j] = pv[j]; }
        pref(t + 4);
#pragma unroll
        for (int j = 0; j < 4; ++j) {
            int tc = t + j;
            if (tc >= tend) break;
            float x = 0.f;
#pragma unroll
            for (int q = 0; q < 9; ++q) x = fmaf(w9[q], win[j + q], x);
            float hd = fmaf(0.5f, vd, x);
            float sd = (hd >= 1.f) ? 1.f : 0.f;
            vd = (hd >= 1.f) ? 0.f : hd;
            float hg = fmaf(0.5f, vg, cg[j]);
            float sg = (hg >= 1.f) ? 1.f : 0.f;
            vg = (hg >= 1.f) ? 0.f : hg;
            float hl = fmaf(0.5f, vl, cl[j]);
            float sl = (hl >= 1.f) ? 1.f : 0.f;
            vl = (hl >= 1.f) ? 0.f : hl;
            float mix = 0.f;
#pragma unroll
            for (int h2 = 0; h2 < 8; ++h2)
                mix = fmaf(w8[h2], __shfl(sd, h2 * 8 + dl, 64), mix);
            float xy = (sg + sl) + mix;
            float hy = fmaf(0.5f, vy, xy);
            float sy = (hy >= 1.f) ? 1.f : 0.f;
            vy = (hy >= 1.f) ? 0.f : hy;
            if (tc >= t0) sy0[(size_t)tc * 4096 + base] = (unsigned char)sy;
        }
#pragma unroll
        for (int i = 0; i < 8; ++i) win[i] = win[i + 4];
#pragma unroll
        for (int i = 0; i < 4; ++i) win[8 + i] = cv[i];
    }
}

// ---------------------------------------------------------------------------
extern "C" void kernel_launch(void* const* d_in, const int* in_sizes, int n_in,
                              void* d_out, int out_size, void* d_ws, size_t ws_size,
                              hipStream_t stream)
{
    const float* x       = (const float*)d_in[0];
    const float* wq      = (const float*)d_in[1];
    const float* wk      = (const float*)d_in[2];
    const float* wv      = (const float*)d_in[3];
    const float* w_mattn = (const float*)d_in[4];
    const float* w_proj  = (const float*)d_in[5];
    const float* w_dw    = (const float*)d_in[6];
    const float* w_pw    = (const float*)d_in[7];
    const float* bn_g    = (const float*)d_in[8];
    const float* bn_b    = (const float*)d_in[9];
    float* out = (float*)d_out;
    float* ws = (float*)d_ws;

    float gs32 = (float)std::sqrt((double)(64 * 500));
    float gscale = (float)(1.0 / (double)gs32);
    float ls32 = (float)std::sqrt((double)(64 * 41));
    float lscale = (float)(1.0 / (double)ls32);
    const int M = TT * 8;   // 4000

    float* S0 = ws;
    float* S1 = ws + (size_t)NTOT;
    float* S2 = ws + 2 * (size_t)NTOT;
    float* part4   = ws + 3 * (size_t)NTOT;     // 4*262144
    float* ktvBuf  = part4 + 4 * 262144;        // 262144
    float* colpart = ktvBuf + 262144;           // 196608 (64 chunks * 1536 * 2)
    unsigned char* spk = (unsigned char*)(colpart + 196608);
    unsigned char* sq  = spk;
    unsigned char* sk  = spk + (size_t)NTOT;
    unsigned char* sv  = spk + 2 * (size_t)NTOT;
    unsigned char* sy0 = spk + 3 * (size_t)NTOT;
    unsigned char* sy1 = spk + 4 * (size_t)NTOT;

    // 1) QKV GEMM (XCD-swizzled 1D grid 768, fused stats, chunk 63 = zeros)
    gemm_f_k<<<768, 256, 0, stream>>>(x, wq, wk, wv, S0, colpart, M);
    // 2) segmented BN+LIF (inline stats finalize, 64 chunks) -> q,k,v byte spikes
    lif_seg_k<<<dim3(48, 5), 256, 0, stream>>>(S0, colpart, 1536, 64, bn_g, bn_b,
                                               nullptr, sq, 100, 64);
    // 3) global branch
    ktv_part_k<<<dim3(64, 4), 256, 0, stream>>>(sk, sv, part4);
    ktv_reduce_k<<<256, 256, 0, stream>>>(part4, ktvBuf);
    gapply_t_k<<<dim3(50, 8), 256, 0, stream>>>(sq, ktvBuf, S0, gscale);      // g_pre -> S0
    // 4) local branch -> l_pre S1
    local_k<<<dim3(16, 64), 256, 0, stream>>>(sq, sk, sv, S1, lscale);
    // 5) fused g/l/dw LIFs + mix + y0 LIF -> sy0 bytes
    branch_y0_k<<<dim3(16, 10), 256, 0, stream>>>(S0, S1, sv, w_dw, w_pw, sy0, 50, 64);
    // 6) mattn GEMM (byte A, XCD-swizzled 256 blocks = 1/CU) -> S2; LIF -> sy1
    gemm_b_k<<<256, 256, 0, stream>>>(sy0, w_mattn, S2, colpart, M);
    lif_seg_k<<<dim3(16, 10), 256, 0, stream>>>(S2, colpart, 512, 64, bn_g + 1536,
                                                bn_b + 1536, nullptr, sy1, 50, 64);
    // 7) proj GEMM -> S0; LIF -> out (fp32)
    gemm_b_k<<<256, 256, 0, stream>>>(sy1, w_proj, S0, colpart, M);
    lif_seg_k<<<dim3(16, 10), 256, 0, stream>>>(S0, colpart, 512, 64, bn_g + 2048,
                                                bn_b + 2048, out, nullptr, 50, 64);

    (void)in_sizes; (void)n_in; (void)out_size; (void)ws_size;
}

// Round 10
// 404.625 us; speedup vs baseline: 1.1643x; 1.0704x over previous
//
#include <hip/hip_runtime.h>
#include <cmath>

#define TT 500
#define NTOT 2048000       // T*B*C elements
#define WW 20

// ---------------------------------------------------------------------------
// QKV GEMM: A fp32 [M,512], 3 weights. BM=64,BN=128,BK=32, 4x8 microtile,
// 256 threads. 1D grid 768, XCD swizzle (unchanged from round 9: 87.5 us).
// ---------------------------------------------------------------------------
__global__ __launch_bounds__(256) void gemm_f_k(
    const float* __restrict__ A,
    const float* __restrict__ W0, const float* __restrict__ W1, const float* __restrict__ W2,
    float* __restrict__ out, float* __restrict__ colpart, int M)
{
    __shared__ __align__(16) float smem[6400];   // As[32][68] | Bs[32][132]; red aliases
    float* As = smem;
    float* Bs = smem + 2176;
    int tid = threadIdx.x;
    int bid = blockIdx.x;
    int xcd = bid & 7;
    int j = bid >> 3;                 // 0..95
    int mblk = (xcd << 3) | (j & 7);  // 0..63
    int nblk = j >> 3;                // 0..11
    int mBase = mblk * 64;
    int nBase = nblk * 128;
    int wsel = nBase >> 9;
    const float* Wp = (wsel == 0) ? W0 : ((wsel == 1) ? W1 : W2);
    int col0 = nBase & 511;
    int ty = tid >> 4, tx = tid & 15;
    int ldRow = tid >> 2;          // 0..63
    int ldK = (tid & 3) * 4;       // 0,4,8,12
    float acc[4][8] = {};
    float4 pa[2], pb[2][2];

    auto loadT = [&](int kt) {
        int m = mBase + ldRow;
        if (m < M) {
            const float* ap = A + (size_t)m * 512 + kt + ldK;
            pa[0] = *(const float4*)ap;
            pa[1] = *(const float4*)(ap + 16);
        } else {
            pa[0] = make_float4(0.f, 0.f, 0.f, 0.f);
            pa[1] = make_float4(0.f, 0.f, 0.f, 0.f);
        }
#pragma unroll
        for (int l = 0; l < 2; ++l) {
            const float* bp = Wp + (size_t)(col0 + ldRow + l * 64) * 512 + kt + ldK;
            pb[l][0] = *(const float4*)bp;
            pb[l][1] = *(const float4*)(bp + 16);
        }
    };
    loadT(0);
    for (int kt = 0; kt < 512; kt += 32) {
        __syncthreads();
#pragma unroll
        for (int g = 0; g < 2; ++g) {
            As[(ldK + 16 * g + 0) * 68 + ldRow] = pa[g].x;
            As[(ldK + 16 * g + 1) * 68 + ldRow] = pa[g].y;
            As[(ldK + 16 * g + 2) * 68 + ldRow] = pa[g].z;
            As[(ldK + 16 * g + 3) * 68 + ldRow] = pa[g].w;
        }
#pragma unroll
        for (int l = 0; l < 2; ++l)
#pragma unroll
            for (int g = 0; g < 2; ++g) {
                int row = ldRow + l * 64;
                Bs[(ldK + 16 * g + 0) * 132 + row] = pb[l][g].x;
                Bs[(ldK + 16 * g + 1) * 132 + row] = pb[l][g].y;
                Bs[(ldK + 16 * g + 2) * 132 + row] = pb[l][g].z;
                Bs[(ldK + 16 * g + 3) * 132 + row] = pb[l][g].w;
            }
        __syncthreads();
        if (kt + 32 < 512) loadT(kt + 32);
#pragma unroll
        for (int kk = 0; kk < 32; ++kk) {
            float4 a0 = *(const float4*)&As[kk * 68 + ty * 4];
            float4 b0 = *(const float4*)&Bs[kk * 132 + tx * 4];
            float4 b1 = *(const float4*)&Bs[kk * 132 + 64 + tx * 4];
            float av[4] = {a0.x, a0.y, a0.z, a0.w};
            float bv[8] = {b0.x, b0.y, b0.z, b0.w, b1.x, b1.y, b1.z, b1.w};
#pragma unroll
            for (int i = 0; i < 4; ++i)
#pragma unroll
                for (int jj = 0; jj < 8; ++jj)
                    acc[i][jj] = fmaf(av[i], bv[jj], acc[i][jj]);
        }
    }
    __syncthreads();   // reuse smem as red[16][128][2]
#pragma unroll
    for (int jj = 0; jj < 8; ++jj) {
        int colL = (jj < 4) ? (tx * 4 + jj) : (64 + tx * 4 + (jj - 4));
        float s = 0.f, q = 0.f;
#pragma unroll
        for (int i = 0; i < 4; ++i) { float v = acc[i][jj]; s += v; q = fmaf(v, v, q); }
        smem[(ty * 128 + colL) * 2 + 0] = s;
        smem[(ty * 128 + colL) * 2 + 1] = q;
    }
    __syncthreads();
    if (tid < 128) {
        float ss = 0.f, qq = 0.f;
#pragma unroll
        for (int r = 0; r < 16; ++r) {
            ss += smem[(r * 128 + tid) * 2 + 0];
            qq += smem[(r * 128 + tid) * 2 + 1];
        }
        colpart[((size_t)mblk * 1536 + nBase + tid) * 2 + 0] = ss;
        colpart[((size_t)mblk * 1536 + nBase + tid) * 2 + 1] = qq;
    }
    float* outp = out + (size_t)wsel * NTOT;
#pragma unroll
    for (int i = 0; i < 4; ++i) {
        int m = mBase + ty * 4 + i;
        if (m < M) {
            *(float4*)(outp + (size_t)m * 512 + col0 + tx * 4) =
                make_float4(acc[i][0], acc[i][1], acc[i][2], acc[i][3]);
            *(float4*)(outp + (size_t)m * 512 + col0 + 64 + tx * 4) =
                make_float4(acc[i][4], acc[i][5], acc[i][6], acc[i][7]);
        }
    }
}

// ---------------------------------------------------------------------------
// Spike-input GEMM: A uchar [M,512]. BM=64,BN=64,BK=32, 4x4 microtile,
// 256 threads. Grid 512 (XCD-swizzled) = 2 blocks/CU, 2 waves/SIMD —
// max parallelism with full-K-per-block (needed for fused stats).
// ---------------------------------------------------------------------------
__global__ __launch_bounds__(256) void gemm_b_k(
    const unsigned char* __restrict__ A, const float* __restrict__ W,
    float* __restrict__ out, float* __restrict__ colpart, int M)
{
    __shared__ __align__(16) float smem[4352];   // As[32][68] | Bs[32][68]; red aliases
    float* As = smem;
    float* Bs = smem + 2176;
    int tid = threadIdx.x;
    int bid = blockIdx.x;
    int xcd = bid & 7;
    int j = bid >> 3;                 // 0..63
    int mblk = (xcd << 3) | (j & 7);  // 0..63
    int nblk = j >> 3;                // 0..7
    int mBase = mblk * 64;
    int col0 = nblk * 64;
    int ty = tid >> 4, tx = tid & 15;
    int ldRow = tid >> 2;          // 0..63
    int ldK = (tid & 3) * 4;       // 0,4,8,12
    float acc[4][4] = {};
    uchar4 pa[2];
    float4 pb[2];

    auto loadT = [&](int kt) {
        int m = mBase + ldRow;
        if (m < M) {
            pa[0] = *(const uchar4*)(A + (size_t)m * 512 + kt + ldK);
            pa[1] = *(const uchar4*)(A + (size_t)m * 512 + kt + 16 + ldK);
        } else {
            pa[0] = make_uchar4(0, 0, 0, 0); pa[1] = make_uchar4(0, 0, 0, 0);
        }
        const float* bp = W + (size_t)(col0 + ldRow) * 512 + kt + ldK;
        pb[0] = *(const float4*)bp;
        pb[1] = *(const float4*)(bp + 16);
    };
    loadT(0);
    for (int kt = 0; kt < 512; kt += 32) {
        __syncthreads();
#pragma unroll
        for (int g = 0; g < 2; ++g) {
            As[(ldK + 16 * g + 0) * 68 + ldRow] = (float)pa[g].x;
            As[(ldK + 16 * g + 1) * 68 + ldRow] = (float)pa[g].y;
            As[(ldK + 16 * g + 2) * 68 + ldRow] = (float)pa[g].z;
            As[(ldK + 16 * g + 3) * 68 + ldRow] = (float)pa[g].w;
            float4 bv4 = pb[g];
            Bs[(ldK + 16 * g + 0) * 68 + ldRow] = bv4.x;
            Bs[(ldK + 16 * g + 1) * 68 + ldRow] = bv4.y;
            Bs[(ldK + 16 * g + 2) * 68 + ldRow] = bv4.z;
            Bs[(ldK + 16 * g + 3) * 68 + ldRow] = bv4.w;
        }
        __syncthreads();
        if (kt + 32 < 512) loadT(kt + 32);
#pragma unroll
        for (int kk = 0; kk < 32; ++kk) {
            float4 a0 = *(const float4*)&As[kk * 68 + ty * 4];
            float4 b0 = *(const float4*)&Bs[kk * 68 + tx * 4];
            float av[4] = {a0.x, a0.y, a0.z, a0.w};
            float bv[4] = {b0.x, b0.y, b0.z, b0.w};
#pragma unroll
            for (int i = 0; i < 4; ++i)
#pragma unroll
                for (int jj = 0; jj < 4; ++jj)
                    acc[i][jj] = fmaf(av[i], bv[jj], acc[i][jj]);
        }
    }
    __syncthreads();   // reuse smem as red[16][64][2]
#pragma unroll
    for (int jj = 0; jj < 4; ++jj) {
        float s = 0.f, q = 0.f;
#pragma unroll
        for (int i = 0; i < 4; ++i) { float v = acc[i][jj]; s += v; q = fmaf(v, v, q); }
        smem[(ty * 64 + tx * 4 + jj) * 2 + 0] = s;
        smem[(ty * 64 + tx * 4 + jj) * 2 + 1] = q;
    }
    __syncthreads();
    if (tid < 64) {
        float ss = 0.f, qq = 0.f;
#pragma unroll
        for (int r = 0; r < 16; ++r) {
            ss += smem[(r * 64 + tid) * 2 + 0];
            qq += smem[(r * 64 + tid) * 2 + 1];
        }
        colpart[((size_t)mblk * 512 + col0 + tid) * 2 + 0] = ss;
        colpart[((size_t)mblk * 512 + col0 + tid) * 2 + 1] = qq;
    }
#pragma unroll
    for (int i = 0; i < 4; ++i) {
        int m = mBase + ty * 4 + i;
        if (m < M)
            *(float4*)(out + (size_t)m * 512 + col0 + tx * 4) =
                make_float4(acc[i][0], acc[i][1], acc[i][2], acc[i][3]);
    }
}

// ---------------------------------------------------------------------------
// Time-segmented BN+LIF with INLINE stats finalize (f64, identical math).
// ---------------------------------------------------------------------------
__global__ __launch_bounds__(256) void lif_seg_k(
    const float* __restrict__ pre, const float* __restrict__ colpart, int CT, int chunks,
    const float* __restrict__ gamma, const float* __restrict__ beta,
    float* __restrict__ outF, unsigned char* __restrict__ outB, int segLen, int warm)
{
    int gid = blockIdx.x * 256 + threadIdx.x;
    int tensor = gid >> 12;
    int bc = gid & 4095;
    int ch = (tensor << 9) | (bc & 511);
    double s = 0.0, s2 = 0.0;
    for (int k = 0; k < chunks; ++k) {
        s  += (double)colpart[((size_t)k * CT + ch) * 2 + 0];
        s2 += (double)colpart[((size_t)k * CT + ch) * 2 + 1];
    }
    double mean = s / 4000.0;
    double var = s2 / 4000.0 - mean * mean;
    double scd = (double)gamma[ch] / sqrt(var + 1e-5);
    float sc = (float)scd;
    float sh = (float)((double)beta[ch] - mean * scd);
    const float* q0 = pre + (size_t)tensor * NTOT + bc;
    float* oF = outF ? outF + (size_t)tensor * NTOT + bc : nullptr;
    unsigned char* oB = outB ? outB + (size_t)tensor * NTOT + bc : nullptr;
    int t0 = blockIdx.y * segLen;
    int twarm = (t0 - warm > 0) ? (t0 - warm) : 0;
    int tend = (t0 + segLen < TT) ? (t0 + segLen) : TT;
    float v = 0.f;
    float b0[8];
#pragma unroll
    for (int j = 0; j < 8; ++j) {
        int tt = twarm + j;
        b0[j] = (tt < tend) ? q0[(size_t)tt * 4096] : 0.f;
    }
    for (int t = twarm; t < tend; t += 8) {
        float n0[8];
#pragma unroll
        for (int j = 0; j < 8; ++j) {
            int tt = t + 8 + j;
            n0[j] = (tt < tend) ? q0[(size_t)tt * 4096] : 0.f;
        }
#pragma unroll
        for (int j = 0; j < 8; ++j) {
            int tc = t + j;
            if (tc >= tend) break;
            float bnx = fmaf(b0[j], sc, sh);
            float h = fmaf(0.5f, v, bnx);
            float sp = (h >= 1.f) ? 1.f : 0.f;
            v = (h >= 1.f) ? 0.f : h;
            if (tc >= t0) {
                if (oB) oB[(size_t)tc * 4096] = (unsigned char)sp;
                else    oF[(size_t)tc * 4096] = sp;
            }
        }
#pragma unroll
        for (int j = 0; j < 8; ++j) b0[j] = n0[j];
    }
}

// ---------------------------------------------------------------------------
// KtV partials over t-quarters from byte spikes (exact integer sums).
// ---------------------------------------------------------------------------
__global__ __launch_bounds__(256) void ktv_part_k(
    const unsigned char* __restrict__ kspk, const unsigned char* __restrict__ vspk,
    float* __restrict__ part)
{
    __shared__ __align__(16) float kb[16][64], vb[16][64];
    int bh = blockIdx.x;
    int seg = blockIdx.y;
    int t0p = seg * 125, t1p = t0p + 125;
    int b = bh >> 3, h = bh & 7;
    int tid = threadIdx.x;
    int d1b = (tid >> 4) * 4, d2b = (tid & 15) * 4;
    size_t cb = (size_t)b * 512 + h * 64;
    int sRow = tid >> 4;
    int sD = (tid & 15) * 4;
    float acc[4][4] = {};
    uchar4 pk, pv;
    auto preload = [&](int tt) {
        int t = tt + sRow;
        if (t < t1p) {
            pk = *(const uchar4*)(kspk + (size_t)t * 4096 + cb + sD);
            pv = *(const uchar4*)(vspk + (size_t)t * 4096 + cb + sD);
        } else {
            pk = make_uchar4(0, 0, 0, 0); pv = make_uchar4(0, 0, 0, 0);
        }
    };
    preload(t0p);
    for (int tt = t0p; tt < t1p; tt += 16) {
        __syncthreads();
        kb[sRow][sD + 0] = (float)pk.x; kb[sRow][sD + 1] = (float)pk.y;
        kb[sRow][sD + 2] = (float)pk.z; kb[sRow][sD + 3] = (float)pk.w;
        vb[sRow][sD + 0] = (float)pv.x; vb[sRow][sD + 1] = (float)pv.y;
        vb[sRow][sD + 2] = (float)pv.z; vb[sRow][sD + 3] = (float)pv.w;
        __syncthreads();
        preload(tt + 16);
#pragma unroll
        for (int tl = 0; tl < 16; ++tl) {
            float4 k4 = *(const float4*)&kb[tl][d1b];
            float4 v4 = *(const float4*)&vb[tl][d2b];
            float ka[4] = {k4.x, k4.y, k4.z, k4.w};
            float va[4] = {v4.x, v4.y, v4.z, v4.w};
#pragma unroll
            for (int i = 0; i < 4; ++i)
#pragma unroll
                for (int j = 0; j < 4; ++j)
                    acc[i][j] = fmaf(ka[i], va[j], acc[i][j]);
        }
    }
    size_t ob = ((size_t)seg * 64 + bh) * 4096;
#pragma unroll
    for (int i = 0; i < 4; ++i)
        *(float4*)(part + ob + (size_t)(d1b + i) * 64 + d2b) =
            make_float4(acc[i][0], acc[i][1], acc[i][2], acc[i][3]);
}

__global__ __launch_bounds__(256) void ktv_reduce_k(
    const float* __restrict__ part, float* __restrict__ ktv)
{
    int i4 = (blockIdx.x * 256 + threadIdx.x) * 4;
    float4 a = *(const float4*)(part + i4);
    float4 b = *(const float4*)(part + 262144 + i4);
    float4 c = *(const float4*)(part + 2 * 262144 + i4);
    float4 d = *(const float4*)(part + 3 * 262144 + i4);
    *(float4*)(ktv + i4) = make_float4(((a.x + b.x) + c.x) + d.x,
                                       ((a.y + b.y) + c.y) + d.y,
                                       ((a.z + b.z) + c.z) + d.z,
                                       ((a.w + b.w) + c.w) + d.w);
}

// ---------------------------------------------------------------------------
// Global attention apply, t-tiled x10.
// ---------------------------------------------------------------------------
__global__ __launch_bounds__(256) void gapply_t_k(
    const unsigned char* __restrict__ sq, const float* __restrict__ ktv,
    float* __restrict__ gpre, float gscale)
{
    __shared__ float qs[10][512];
    int tid = threadIdx.x;
    int t0 = blockIdx.x * 10;
    int b = blockIdx.y;
    for (int i = tid; i < 1280; i += 256) {
        int t = i >> 7;
        int c4 = (i & 127) * 4;
        uchar4 u = *(const uchar4*)(sq + (size_t)(t0 + t) * 4096 + b * 512 + c4);
        qs[t][c4 + 0] = (float)u.x; qs[t][c4 + 1] = (float)u.y;
        qs[t][c4 + 2] = (float)u.z; qs[t][c4 + 3] = (float)u.w;
    }
    __syncthreads();
#pragma unroll
    for (int half = 0; half < 2; ++half) {
        int c = tid + half * 256;
        int h = c >> 6, dcol = c & 63;
        const float* kt = ktv + ((size_t)(b * 8 + h) * 64) * 64 + dcol;
        float acc[10] = {};
        for (int d1 = 0; d1 < 64; ++d1) {
            float kv = kt[(size_t)d1 * 64];
#pragma unroll
            for (int t = 0; t < 10; ++t)
                acc[t] = fmaf(qs[t][h * 64 + d1], kv, acc[t]);
        }
#pragma unroll
        for (int t = 0; t < 10; ++t)
            gpre[(size_t)(t0 + t) * 4096 + b * 512 + c] = acc[t] * gscale;
    }
}

// ---------------------------------------------------------------------------
// Local banded attention; LDS padded to 68 cols.
// ---------------------------------------------------------------------------
__global__ __launch_bounds__(256) void local_k(
    const unsigned char* __restrict__ qspk, const unsigned char* __restrict__ kspk,
    const unsigned char* __restrict__ vspk, float* __restrict__ lpre, float lscale)
{
    __shared__ __align__(16) float qs[32][68];
    __shared__ __align__(16) float ks[72][68];
    __shared__ __align__(16) float vs[72][68];
    __shared__ float sm[32][72];
    int t0 = blockIdx.x * 32;
    int bh = blockIdx.y;
    int b = bh >> 3, h = bh & 7;
    int tid = threadIdx.x;
    size_t cb = (size_t)b * 512 + h * 64;

    for (int i = tid; i < 512; i += 256) {
        int r = i >> 4, d4 = (i & 15) * 4;
        int t = t0 + r;
        if (t < TT) {
            uchar4 u = *(const uchar4*)(qspk + (size_t)t * 4096 + cb + d4);
            qs[r][d4 + 0] = (float)u.x; qs[r][d4 + 1] = (float)u.y;
            qs[r][d4 + 2] = (float)u.z; qs[r][d4 + 3] = (float)u.w;
        } else {
            qs[r][d4 + 0] = 0.f; qs[r][d4 + 1] = 0.f; qs[r][d4 + 2] = 0.f; qs[r][d4 + 3] = 0.f;
        }
    }
    for (int i = tid; i < 1152; i += 256) {
        int r = i >> 4, d4 = (i & 15) * 4;
        int u_ = t0 - WW + r;
        if (u_ >= 0 && u_ < TT) {
            uchar4 uk = *(const uchar4*)(kspk + (size_t)u_ * 4096 + cb + d4);
            uchar4 uv = *(const uchar4*)(vspk + (size_t)u_ * 4096 + cb + d4);
            ks[r][d4 + 0] = (float)uk.x; ks[r][d4 + 1] = (float)uk.y;
            ks[r][d4 + 2] = (float)uk.z; ks[r][d4 + 3] = (float)uk.w;
            vs[r][d4 + 0] = (float)uv.x; vs[r][d4 + 1] = (float)uv.y;
            vs[r][d4 + 2] = (float)uv.z; vs[r][d4 + 3] = (float)uv.w;
        } else {
            ks[r][d4 + 0] = 0.f; ks[r][d4 + 1] = 0.f; ks[r][d4 + 2] = 0.f; ks[r][d4 + 3] = 0.f;
            vs[r][d4 + 0] = 0.f; vs[r][d4 + 1] = 0.f; vs[r][d4 + 2] = 0.f; vs[r][d4 + 3] = 0.f;
        }
    }
    __syncthreads();

    int tA = tid >> 3;
    int ug = tid & 7;
    float4 qreg[16];
#pragma unroll
    for (int i = 0; i < 16; ++i) qreg[i] = *(const float4*)&qs[tA][i * 4];
#pragma unroll
    for (int ui = 0; ui < 9; ++ui) {
        int u = ug + ui * 8;
        float acc = 0.f;
#pragma unroll
        for (int i = 0; i < 16; ++i) {
            float4 k4 = *(const float4*)&ks[u][i * 4];
            acc = fmaf(qreg[i].x, k4.x, acc);
            acc = fmaf(qreg[i].y, k4.y, acc);
            acc = fmaf(qreg[i].z, k4.z, acc);
            acc = fmaf(qreg[i].w, k4.w, acc);
        }
        sm[tA][u] = acc;
    }
    __syncthreads();

#pragma unroll
    for (int oi = 0; oi < 2; ++oi) {
        int idx = tid + oi * 256;
        int t = idx >> 4;
        int dg = (idx & 15) * 4;
        float4 acc = make_float4(0.f, 0.f, 0.f, 0.f);
        for (int o = 0; o < 41; ++o) {
            int u = t + o;
            float s = sm[t][u];
            float4 v4 = *(const float4*)&vs[u][dg];
            acc.x = fmaf(s, v4.x, acc.x);
            acc.y = fmaf(s, v4.y, acc.y);
            acc.z = fmaf(s, v4.z, acc.z);
            acc.w = fmaf(s, v4.w, acc.w);
        }
        int tg = t0 + t;
        if (tg < TT) {
            acc.x *= lscale; acc.y *= lscale; acc.z *= lscale; acc.w *= lscale;
            *(float4*)(lpre + (size_t)tg * 4096 + cb + dg) = acc;
        }
    }
}

// ---------------------------------------------------------------------------
// Fused branch kernel: g-LIF + l-LIF + dwconv9-LIF + head-mix (wave shfl) +
// y0-LIF.
// ---------------------------------------------------------------------------
__global__ __launch_bounds__(256) void branch_y0_k(
    const float* __restrict__ gpre, const float* __restrict__ lpre,
    const unsigned char* __restrict__ sv, const float* __restrict__ wdw,
    const float* __restrict__ wpw, unsigned char* __restrict__ sy0,
    int segLen, int warm)
{
    int tid = threadIdx.x;
    int wave = tid >> 6, lane = tid & 63;
    int gw = blockIdx.x * 4 + wave;    // 0..63
    int b = gw >> 3, dg = gw & 7;
    int h = lane >> 3, dl = lane & 7;
    int c = h * 64 + dg * 8 + dl;
    int base = b * 512 + c;
    float w9[9];
#pragma unroll
    for (int j = 0; j < 9; ++j) w9[j] = wdw[h * 9 + j];
    float w8[8];
#pragma unroll
    for (int j = 0; j < 8; ++j) w8[j] = wpw[h * 8 + j];
    int t0 = blockIdx.y * segLen;
    int twarm = (t0 - warm > 0) ? (t0 - warm) : 0;
    int tend = (t0 + segLen < TT) ? (t0 + segLen) : TT;
    float vg = 0.f, vl = 0.f, vd = 0.f, vy = 0.f;
    float win[12];
#pragma unroll
    for (int i = 0; i < 12; ++i) {
        int tt = twarm - 4 + i;
        win[i] = (tt >= 0 && tt < TT) ? (float)sv[(size_t)tt * 4096 + base] : 0.f;
    }
    float pg[4], pl[4], pv[4];
    auto pref = [&](int t) {
#pragma unroll
        for (int j = 0; j < 4; ++j) {
            int tt = t + j;
            bool in = tt < tend;
            pg[j] = in ? gpre[(size_t)tt * 4096 + base] : 0.f;
            pl[j] = in ? lpre[(size_t)tt * 4096 + base] : 0.f;
            int tv = t + 8 + j;
            pv[j] = (tv < TT) ? (float)sv[(size_t)tv * 4096 + base] : 0.f;
        }
    };
    pref(twarm);
    for (int t = twarm; t < tend; t += 4) {
        float cg[4], cl[4], cv[4];
#pragma unroll
        for (int j = 0; j < 4; ++j) { cg[j] = pg[j]; cl[j] = pl[j]; cv[j] = pv[j]; }
        pref(t + 4);
#pragma unroll
        for (int j = 0; j < 4; ++j) {
            int tc = t + j;
            if (tc >= tend) break;
            float x = 0.f;
#pragma unroll
            for (int q = 0; q < 9; ++q) x = fmaf(w9[q], win[j + q], x);
            float hd = fmaf(0.5f, vd, x);
            float sd = (hd >= 1.f) ? 1.f : 0.f;
            vd = (hd >= 1.f) ? 0.f : hd;
            float hg = fmaf(0.5f, vg, cg[j]);
            float sg = (hg >= 1.f) ? 1.f : 0.f;
            vg = (hg >= 1.f) ? 0.f : hg;
            float hl = fmaf(0.5f, vl, cl[j]);
            float sl = (hl >= 1.f) ? 1.f : 0.f;
            vl = (hl >= 1.f) ? 0.f : hl;
            float mix = 0.f;
#pragma unroll
            for (int h2 = 0; h2 < 8; ++h2)
                mix = fmaf(w8[h2], __shfl(sd, h2 * 8 + dl, 64), mix);
            float xy = (sg + sl) + mix;
            float hy = fmaf(0.5f, vy, xy);
            float sy = (hy >= 1.f) ? 1.f : 0.f;
            vy = (hy >= 1.f) ? 0.f : hy;
            if (tc >= t0) sy0[(size_t)tc * 4096 + base] = (unsigned char)sy;
        }
#pragma unroll
        for (int i = 0; i < 8; ++i) win[i] = win[i + 4];
#pragma unroll
        for (int i = 0; i < 4; ++i) win[8 + i] = cv[i];
    }
}

// ---------------------------------------------------------------------------
extern "C" void kernel_launch(void* const* d_in, const int* in_sizes, int n_in,
                              void* d_out, int out_size, void* d_ws, size_t ws_size,
                              hipStream_t stream)
{
    const float* x       = (const float*)d_in[0];
    const float* wq      = (const float*)d_in[1];
    const float* wk      = (const float*)d_in[2];
    const float* wv      = (const float*)d_in[3];
    const float* w_mattn = (const float*)d_in[4];
    const float* w_proj  = (const float*)d_in[5];
    const float* w_dw    = (const float*)d_in[6];
    const float* w_pw    = (const float*)d_in[7];
    const float* bn_g    = (const float*)d_in[8];
    const float* bn_b    = (const float*)d_in[9];
    float* out = (float*)d_out;
    float* ws = (float*)d_ws;

    float gs32 = (float)std::sqrt((double)(64 * 500));
    float gscale = (float)(1.0 / (double)gs32);
    float ls32 = (float)std::sqrt((double)(64 * 41));
    float lscale = (float)(1.0 / (double)ls32);
    const int M = TT * 8;   // 4000

    float* S0 = ws;
    float* S1 = ws + (size_t)NTOT;
    float* S2 = ws + 2 * (size_t)NTOT;
    float* part4   = ws + 3 * (size_t)NTOT;     // 4*262144
    float* ktvBuf  = part4 + 4 * 262144;        // 262144
    float* colpart = ktvBuf + 262144;           // 196608 (64 chunks * 1536 * 2)
    unsigned char* spk = (unsigned char*)(colpart + 196608);
    unsigned char* sq  = spk;
    unsigned char* sk  = spk + (size_t)NTOT;
    unsigned char* sv  = spk + 2 * (size_t)NTOT;
    unsigned char* sy0 = spk + 3 * (size_t)NTOT;
    unsigned char* sy1 = spk + 4 * (size_t)NTOT;

    // 1) QKV GEMM (XCD-swizzled 768 blocks, fused stats)
    gemm_f_k<<<768, 256, 0, stream>>>(x, wq, wk, wv, S0, colpart, M);
    // 2) segmented BN+LIF, seg=50 -> 480 blocks
    lif_seg_k<<<dim3(48, 10), 256, 0, stream>>>(S0, colpart, 1536, 64, bn_g, bn_b,
                                                nullptr, sq, 50, 64);
    // 3) global branch
    ktv_part_k<<<dim3(64, 4), 256, 0, stream>>>(sk, sv, part4);
    ktv_reduce_k<<<256, 256, 0, stream>>>(part4, ktvBuf);
    gapply_t_k<<<dim3(50, 8), 256, 0, stream>>>(sq, ktvBuf, S0, gscale);      // g_pre -> S0
    // 4) local branch -> l_pre S1
    local_k<<<dim3(16, 64), 256, 0, stream>>>(sq, sk, sv, S1, lscale);
    // 5) fused g/l/dw LIFs + mix + y0 LIF, seg=25 -> 320 blocks
    branch_y0_k<<<dim3(16, 20), 256, 0, stream>>>(S0, S1, sv, w_dw, w_pw, sy0, 25, 64);
    // 6) mattn GEMM (byte A, 512 swizzled blocks = 2/CU) -> S2; LIF seg=25
    gemm_b_k<<<512, 256, 0, stream>>>(sy0, w_mattn, S2, colpart, M);
    lif_seg_k<<<dim3(16, 20), 256, 0, stream>>>(S2, colpart, 512, 64, bn_g + 1536,
                                                bn_b + 1536, nullptr, sy1, 25, 64);
    // 7) proj GEMM -> S0; LIF -> out (fp32), seg=25
    gemm_b_k<<<512, 256, 0, stream>>>(sy1, w_proj, S0, colpart, M);
    lif_seg_k<<<dim3(16, 20), 256, 0, stream>>>(S0, colpart, 512, 64, bn_g + 2048,
                                                bn_b + 2048, out, nullptr, 25, 64);

    (void)in_sizes; (void)n_in; (void)out_size; (void)ws_size;
}